// Round 12
// baseline (206.956 us; speedup 1.0000x reference)
//
#include <hip/hip_runtime.h>
#include <math.h>

#define HID 256
#define HEADS 8
#define HD 32
#define C_CLUST 1000
#define SCALEQ 0.17677669529663687f /* 1/sqrt(32) */
#define CAP 512                     /* max cluster size; true max ~253 (multinomial) */
#define NW 8                        /* waves per pool block (512 threads) */
#define SCORE_BLOCKS 2048           /* 8192 waves; strip = ceil(N/8192) rows/wave */

typedef float fx4 __attribute__((ext_vector_type(4)));

// ---- prep: qk[8][256] = scale*Wk_head^T q ; cb[8]; zero cur ----
__global__ __launch_bounds__(256) void k_prep(const float* __restrict__ Wk,
                                              const float* __restrict__ bk,
                                              const float* __restrict__ pq,
                                              float* __restrict__ qk,
                                              float* __restrict__ cb,
                                              int* __restrict__ cur) {
  __shared__ float qv[HD];
  int h = blockIdx.x;
  int t = threadIdx.x;
  int g = h * 256 + t;
  for (int i = g; i < C_CLUST; i += 2048) cur[i] = 0;
  if (t < HD) qv[t] = pq[h * HD + t];
  __syncthreads();
  float a = 0.f;
#pragma unroll 8
  for (int d = 0; d < HD; ++d) a += Wk[(size_t)(h * HD + d) * HID + t] * qv[d];
  qk[h * HID + t] = a * SCALEQ;
  if (t == 0) {
    float s = 0.f;
    for (int d = 0; d < HD; ++d) s += bk[h * HD + d] * qv[d];
    cb[h] = s * SCALEQ;
  }
}

// ---- scores: STRIP-streaming read of x; e[8] -> es (seq per wave); index scatter ----
__global__ __launch_bounds__(256) void k_scores(const float* __restrict__ x,
                                                const int* __restrict__ seg,
                                                const float* __restrict__ qk,
                                                const float* __restrict__ cb,
                                                float* __restrict__ es,
                                                int* __restrict__ cur,
                                                int* __restrict__ list, int N) {
  int l = threadIdx.x & 63;
  int wv = (int)(((size_t)blockIdx.x * blockDim.x + threadIdx.x) >> 6);
  int nwv = (int)(((size_t)gridDim.x * blockDim.x) >> 6);
  int strip = (N + nwv - 1) / nwv;
  int n0 = wv * strip;
  int n1 = n0 + strip;
  if (n1 > N) n1 = N;
  float4 q4[8];
#pragma unroll
  for (int h = 0; h < 8; ++h) q4[h] = *(const float4*)(qk + h * HID + 4 * l);
  float cbv = cb[l & 7];
#pragma unroll 2
  for (int n = n0; n < n1; ++n) {
    float4 xv = *(const float4*)(x + (size_t)n * HID + 4 * l);
    float r0 = xv.x * q4[0].x + xv.y * q4[0].y + xv.z * q4[0].z + xv.w * q4[0].w;
    float r1 = xv.x * q4[1].x + xv.y * q4[1].y + xv.z * q4[1].z + xv.w * q4[1].w;
    float r2 = xv.x * q4[2].x + xv.y * q4[2].y + xv.z * q4[2].z + xv.w * q4[2].w;
    float r3 = xv.x * q4[3].x + xv.y * q4[3].y + xv.z * q4[3].z + xv.w * q4[3].w;
    float r4 = xv.x * q4[4].x + xv.y * q4[4].y + xv.z * q4[4].z + xv.w * q4[4].w;
    float r5 = xv.x * q4[5].x + xv.y * q4[5].y + xv.z * q4[5].z + xv.w * q4[5].w;
    float r6 = xv.x * q4[6].x + xv.y * q4[6].y + xv.z * q4[6].z + xv.w * q4[6].w;
    float r7 = xv.x * q4[7].x + xv.y * q4[7].y + xv.z * q4[7].z + xv.w * q4[7].w;
    r0 += __shfl_xor(r0, 1); r0 += __shfl_xor(r0, 2); r0 += __shfl_xor(r0, 4);
    r1 += __shfl_xor(r1, 1); r1 += __shfl_xor(r1, 2); r1 += __shfl_xor(r1, 4);
    r2 += __shfl_xor(r2, 1); r2 += __shfl_xor(r2, 2); r2 += __shfl_xor(r2, 4);
    r3 += __shfl_xor(r3, 1); r3 += __shfl_xor(r3, 2); r3 += __shfl_xor(r3, 4);
    r4 += __shfl_xor(r4, 1); r4 += __shfl_xor(r4, 2); r4 += __shfl_xor(r4, 4);
    r5 += __shfl_xor(r5, 1); r5 += __shfl_xor(r5, 2); r5 += __shfl_xor(r5, 4);
    r6 += __shfl_xor(r6, 1); r6 += __shfl_xor(r6, 2); r6 += __shfl_xor(r6, 4);
    r7 += __shfl_xor(r7, 1); r7 += __shfl_xor(r7, 2); r7 += __shfl_xor(r7, 4);
    int p = l & 7;
    float v = (p < 4) ? ((p < 2) ? (p == 0 ? r0 : r1) : (p == 2 ? r2 : r3))
                      : ((p < 6) ? (p == 4 ? r4 : r5) : (p == 6 ? r6 : r7));
    v += __shfl_xor(v, 8); v += __shfl_xor(v, 16); v += __shfl_xor(v, 32);
    v += cbv;
    // softmax weights e/z are invariant to max subtraction; |s|<=~20 is f32-safe
    if (l < 8) es[(size_t)n * 8 + l] = __expf(v);
    if (l == 0) {
      int c = seg[n];
      int pos = atomicAdd(&cur[c], 1);
      if (pos < CAP) list[c * CAP + pos] = n;
    }
  }
}

// ---- per-cluster: gather x rows (L3-hot) 8-deep, z + A=Σe·x one pass; GEMVs; outc seq ----
__global__ __launch_bounds__(512) void k_pool(const float* __restrict__ x,
                                              const float* __restrict__ es,
                                              const int* __restrict__ cur,
                                              const int* __restrict__ list,
                                              const float* __restrict__ Wv,
                                              const float* __restrict__ bv,
                                              const float* __restrict__ Wo,
                                              const float* __restrict__ bo,
                                              float* __restrict__ outc) {
  __shared__ float4 buf4[512];     // 8 KB cross-wave reduce
  __shared__ float s_lds[8 * HID]; // 8 KB
  __shared__ float red[NW * 8];
  __shared__ float p_lds[HID];
  int c = blockIdx.x;
  int t = threadIdx.x;
  int cnt = cur[c];
  if (cnt == 0) return;  // empty cluster: never referenced by k_expand
  int cntL = (cnt < CAP) ? cnt : CAP;
  int w = t >> 6, l = t & 63;
  const int* lp = list + c * CAP;

  // one pass: acc[h] += e[h]*x ; zacc[h] += e[h]; 8 rows in flight per wave
  float4 acc[8];
#pragma unroll
  for (int h = 0; h < 8; ++h) acc[h] = make_float4(0.f, 0.f, 0.f, 0.f);
  float zacc[8];
#pragma unroll
  for (int h = 0; h < 8; ++h) zacc[h] = 0.f;
  const float* xb = x + 4 * l;

#define ROW(NI)                                                                \
  { int nn = (NI);                                                             \
    float4 ea = *(const float4*)(es + (size_t)nn * 8);                         \
    float4 eb4 = *(const float4*)(es + (size_t)nn * 8 + 4);                    \
    float4 xv = *(const float4*)(xb + (size_t)nn * HID);                       \
    float eh[8] = {ea.x, ea.y, ea.z, ea.w, eb4.x, eb4.y, eb4.z, eb4.w};        \
    _Pragma("unroll")                                                          \
    for (int h = 0; h < 8; ++h) {                                              \
      acc[h].x += eh[h] * xv.x; acc[h].y += eh[h] * xv.y;                      \
      acc[h].z += eh[h] * xv.z; acc[h].w += eh[h] * xv.w;                      \
      zacc[h] += eh[h]; } }
  int i = w;
  for (; i + 7 * NW < cntL; i += 8 * NW) {
    int n0 = lp[i],          n1 = lp[i + NW],     n2 = lp[i + 2 * NW],
        n3 = lp[i + 3 * NW], n4 = lp[i + 4 * NW], n5 = lp[i + 5 * NW],
        n6 = lp[i + 6 * NW], n7 = lp[i + 7 * NW];
    ROW(n0) ROW(n1) ROW(n2) ROW(n3) ROW(n4) ROW(n5) ROW(n6) ROW(n7)
  }
  for (; i < cntL; i += NW) ROW(lp[i])
#undef ROW

  // per-wave z partials (zacc identical across the wave's lanes)
#pragma unroll
  for (int h = 0; h < 8; ++h)
    if (l == h) red[w * 8 + h] = zacc[h];
  __syncthreads();
  float zinv[8];
#pragma unroll
  for (int h = 0; h < 8; ++h) {
    float z = 0.f;
#pragma unroll
    for (int w2 = 0; w2 < NW; ++w2) z += red[w2 * 8 + h];
    zinv[h] = (z > 0.f) ? 1.f / z : 0.f;
  }

  // cross-wave reduce + normalize -> s_lds[h][col]
#pragma unroll
  for (int h = 0; h < 8; ++h) {
    __syncthreads();
    buf4[t] = acc[h];
    __syncthreads();
    if (t < 64) {
      float4 s = buf4[t];
#pragma unroll
      for (int w2 = 1; w2 < NW; ++w2) {
        float4 b = buf4[w2 * 64 + t];
        s.x += b.x; s.y += b.y; s.z += b.z; s.w += b.w;
      }
      float sc = zinv[h];
      s.x *= sc; s.y *= sc; s.z *= sc; s.w *= sc;
      *(float4*)&s_lds[h * HID + 4 * t] = s;
    }
  }
  __syncthreads();

  // GEMV1: pooled[o] = (Wv[o,:]·S[head(o),:] + bv[o]) / cnt -- 4 lanes/row, 2 rows/thread
  int grp = t >> 2, q = t & 3;
  float rc = 1.f / (float)cnt;
#pragma unroll
  for (int r = 0; r < 2; ++r) {
    int o = grp + 128 * r;
    const float4* wr = (const float4*)(Wv + (size_t)o * HID);
    const float4* sr = (const float4*)(s_lds + (o >> 5) * HID);
    float a = 0.f;
#pragma unroll
    for (int k = 0; k < 16; ++k) {
      float4 w4 = wr[q + 4 * k];
      float4 s4 = sr[q + 4 * k];
      a += w4.x * s4.x + w4.y * s4.y + w4.z * s4.z + w4.w * s4.w;
    }
    a += __shfl_xor(a, 1);
    a += __shfl_xor(a, 2);
    if (q == 0) p_lds[o] = (a + bv[o]) * rc;
  }
  __syncthreads();
  // GEMV2: outc[c][o] = Wo[o,:]·pooled + bo[o]  (1 KB sequential store)
#pragma unroll
  for (int r = 0; r < 2; ++r) {
    int o = grp + 128 * r;
    const float4* wr = (const float4*)(Wo + (size_t)o * HID);
    const float4* pr = (const float4*)p_lds;
    float a = 0.f;
#pragma unroll
    for (int k = 0; k < 16; ++k) {
      float4 w4 = wr[q + 4 * k];
      float4 p4 = pr[q + 4 * k];
      a += w4.x * p4.x + w4.y * p4.y + w4.z * p4.z + w4.w * p4.w;
    }
    a += __shfl_xor(a, 1);
    a += __shfl_xor(a, 2);
    if (q == 0) outc[(size_t)c * HID + o] = a + bo[o];
  }
}

// ---- expand: out[n] = outc[seg[n]] — sequential writes, outc L2-hot ----
__global__ __launch_bounds__(256) void k_expand(const int* __restrict__ seg,
                                                const float* __restrict__ outc,
                                                float* __restrict__ out, int N) {
  size_t g = (size_t)blockIdx.x * blockDim.x + threadIdx.x;
  size_t total = (size_t)N * (HID / 4);
  size_t stride = (size_t)gridDim.x * blockDim.x;
  const float4* oc = (const float4*)outc;
  float4* o4 = (float4*)out;
  for (; g < total; g += stride) {
    int n = (int)(g >> 6);
    int q = (int)(g & 63);
    int c = seg[n];
    o4[g] = oc[(size_t)c * 64 + q];
  }
}

extern "C" void kernel_launch(void* const* d_in, const int* in_sizes, int n_in,
                              void* d_out, int out_size, void* d_ws, size_t ws_size,
                              hipStream_t stream) {
  const float* x = (const float*)d_in[0];
  const int* seg = (const int*)d_in[1];
  // d_in[2] = batch (unused by reference)
  const float* Wk = (const float*)d_in[3];
  const float* bk = (const float*)d_in[4];
  const float* Wv = (const float*)d_in[5];
  const float* bv = (const float*)d_in[6];
  const float* Wo = (const float*)d_in[7];
  const float* bo = (const float*)d_in[8];
  const float* pq = (const float*)d_in[9];
  int N = in_sizes[0] / HID;

  char* ws = (char*)d_ws;
  size_t cur_off = 0;
  auto take = [&](size_t bytes) -> void* {
    void* p = ws + cur_off;
    cur_off += (bytes + 255) & ~(size_t)255;
    return p;
  };
  float* qk = (float*)take((size_t)HEADS * HID * 4);
  float* cb = (float*)take((size_t)HEADS * 4);
  int* cur = (int*)take((size_t)C_CLUST * 4);
  int* list = (int*)take((size_t)C_CLUST * CAP * 4);
  float* es = (float*)take((size_t)N * 8 * 4);
  float* outc = (float*)take((size_t)C_CLUST * HID * 4);

  k_prep<<<HEADS, 256, 0, stream>>>(Wk, bk, pq, qk, cb, cur);
  k_scores<<<SCORE_BLOCKS, 256, 0, stream>>>(x, seg, qk, cb, es, cur, list, N);
  k_pool<<<C_CLUST, 512, 0, stream>>>(x, es, cur, list, Wv, bv, Wo, bo, outc);
  k_expand<<<2048, 256, 0, stream>>>(seg, outc, (float*)d_out, N);
}

// Round 13
// 191.808 us; speedup vs baseline: 1.0790x; 1.0790x over previous
//
#include <hip/hip_runtime.h>
#include <math.h>

#define HID 256
#define HEADS 8
#define HD 32
#define C_CLUST 1000
#define SCALEQ 0.17677669529663687f /* 1/sqrt(32) */
#define CAP 512                     /* max cluster size; true max ~253 (multinomial) */
#define NW 8                        /* waves per pool block (512 threads) */

typedef float fx4 __attribute__((ext_vector_type(4)));

// ---- prep: qk[8][256] = scale*Wk_head^T q ; cb[8]; zero cur ----
__global__ __launch_bounds__(256) void k_prep(const float* __restrict__ Wk,
                                              const float* __restrict__ bk,
                                              const float* __restrict__ pq,
                                              float* __restrict__ qk,
                                              float* __restrict__ cb,
                                              int* __restrict__ cur) {
  __shared__ float qv[HD];
  int h = blockIdx.x;
  int t = threadIdx.x;
  int g = h * 256 + t;
  for (int i = g; i < C_CLUST; i += 2048) cur[i] = 0;
  if (t < HD) qv[t] = pq[h * HD + t];
  __syncthreads();
  float a = 0.f;
#pragma unroll 8
  for (int d = 0; d < HD; ++d) a += Wk[(size_t)(h * HD + d) * HID + t] * qv[d];
  qk[h * HID + t] = a * SCALEQ;
  if (t == 0) {
    float s = 0.f;
    for (int d = 0; d < HD; ++d) s += bk[h * HD + d] * qv[d];
    cb[h] = s * SCALEQ;
  }
}

// ---- scores: 8-row tiles (8 KB contiguous per wave), 10-shuffle butterfly,
//      contiguous 256 B es store, parallel per-row index scatter in lanes 0-7 ----
__global__ __launch_bounds__(256) void k_scores(const float* __restrict__ x,
                                                const int* __restrict__ seg,
                                                const float* __restrict__ qk,
                                                const float* __restrict__ cb,
                                                float* __restrict__ es,
                                                int* __restrict__ cur,
                                                int* __restrict__ list, int N) {
  int l = threadIdx.x & 63;
  int wv = (int)(((size_t)blockIdx.x * blockDim.x + threadIdx.x) >> 6);
  int nwv = (int)(((size_t)gridDim.x * blockDim.x) >> 6);
  float4 q4[8];
#pragma unroll
  for (int h = 0; h < 8; ++h) q4[h] = *(const float4*)(qk + h * HID + 4 * l);
  float cbv = cb[l & 7];
  bool b0 = (l & 1) != 0, b1 = (l & 2) != 0, b2 = (l & 4) != 0;
  int hsel = l >> 3;  // which row of the tile this lane's es value belongs to
  int ntile = (N + 7) >> 3;

// per-row: 8 dots -> butterfly (4+2+1 shuffles) -> broadcast total (3 shuffles)
#define ROWSCORE(XV, OUT)                                                      \
  { float r0 = XV.x * q4[0].x + XV.y * q4[0].y + XV.z * q4[0].z + XV.w * q4[0].w; \
    float r1 = XV.x * q4[1].x + XV.y * q4[1].y + XV.z * q4[1].z + XV.w * q4[1].w; \
    float r2 = XV.x * q4[2].x + XV.y * q4[2].y + XV.z * q4[2].z + XV.w * q4[2].w; \
    float r3 = XV.x * q4[3].x + XV.y * q4[3].y + XV.z * q4[3].z + XV.w * q4[3].w; \
    float r4 = XV.x * q4[4].x + XV.y * q4[4].y + XV.z * q4[4].z + XV.w * q4[4].w; \
    float r5 = XV.x * q4[5].x + XV.y * q4[5].y + XV.z * q4[5].z + XV.w * q4[5].w; \
    float r6 = XV.x * q4[6].x + XV.y * q4[6].y + XV.z * q4[6].z + XV.w * q4[6].w; \
    float r7 = XV.x * q4[7].x + XV.y * q4[7].y + XV.z * q4[7].z + XV.w * q4[7].w; \
    float t0 = (b0 ? r1 : r0) + __shfl_xor(b0 ? r0 : r1, 1);                   \
    float t1 = (b0 ? r3 : r2) + __shfl_xor(b0 ? r2 : r3, 1);                   \
    float t2 = (b0 ? r5 : r4) + __shfl_xor(b0 ? r4 : r5, 1);                   \
    float t3 = (b0 ? r7 : r6) + __shfl_xor(b0 ? r6 : r7, 1);                   \
    float u0 = (b1 ? t1 : t0) + __shfl_xor(b1 ? t0 : t1, 2);                   \
    float u1 = (b1 ? t3 : t2) + __shfl_xor(b1 ? t2 : t3, 2);                   \
    float gg = (b2 ? u1 : u0) + __shfl_xor(b2 ? u0 : u1, 4);                   \
    gg += __shfl_xor(gg, 8);                                                   \
    gg += __shfl_xor(gg, 16);                                                  \
    gg += __shfl_xor(gg, 32);                                                  \
    OUT = gg; }

  for (int tile = wv; tile < ntile; tile += nwv) {
    int n0 = tile * 8;
    float f0, f1, f2, f3, f4, f5, f6, f7;
    if (n0 + 8 <= N) {
      const float* xb = x + (size_t)n0 * HID + 4 * l;
      float4 xv0 = *(const float4*)(xb + 0 * HID);
      float4 xv1 = *(const float4*)(xb + 1 * HID);
      float4 xv2 = *(const float4*)(xb + 2 * HID);
      float4 xv3 = *(const float4*)(xb + 3 * HID);
      float4 xv4 = *(const float4*)(xb + 4 * HID);
      float4 xv5 = *(const float4*)(xb + 5 * HID);
      float4 xv6 = *(const float4*)(xb + 6 * HID);
      float4 xv7 = *(const float4*)(xb + 7 * HID);
      ROWSCORE(xv0, f0) ROWSCORE(xv1, f1) ROWSCORE(xv2, f2) ROWSCORE(xv3, f3)
      ROWSCORE(xv4, f4) ROWSCORE(xv5, f5) ROWSCORE(xv6, f6) ROWSCORE(xv7, f7)
      float fs = (hsel < 4)
                     ? ((hsel < 2) ? (hsel == 0 ? f0 : f1) : (hsel == 2 ? f2 : f3))
                     : ((hsel < 6) ? (hsel == 4 ? f4 : f5) : (hsel == 6 ? f6 : f7));
      // softmax weights e/z are invariant to max subtraction; |s|<=~20 is f32-safe
      es[(size_t)n0 * 8 + l] = __expf(fs + cbv);  // 256 B contiguous wave store
      if (l < 8) {
        int row = n0 + l;
        int c = seg[row];
        int pos = atomicAdd(&cur[c], 1);
        if (pos < CAP) list[c * CAP + pos] = row;
      }
    } else {  // tail tile (never taken when N % 8 == 0)
      float fr[1];
      for (int j = 0; j < 8; ++j) {
        int n = n0 + j;
        float4 xv = make_float4(0.f, 0.f, 0.f, 0.f);
        if (n < N) xv = *(const float4*)(x + (size_t)n * HID + 4 * l);
        ROWSCORE(xv, fr[0])
        if (n < N) {
          float v = fr[0] + cbv;
          if (l < 8) es[(size_t)n * 8 + l] = __expf(v);
          if (l == 0) {
            int c = seg[n];
            int pos = atomicAdd(&cur[c], 1);
            if (pos < CAP) list[c * CAP + pos] = n;
          }
        }
      }
    }
  }
#undef ROWSCORE
}

// ---- per-cluster: gather x rows (L3-hot) 8-deep, z + A=Σe·x one pass; GEMVs; outc seq ----
__global__ __launch_bounds__(512) void k_pool(const float* __restrict__ x,
                                              const float* __restrict__ es,
                                              const int* __restrict__ cur,
                                              const int* __restrict__ list,
                                              const float* __restrict__ Wv,
                                              const float* __restrict__ bv,
                                              const float* __restrict__ Wo,
                                              const float* __restrict__ bo,
                                              float* __restrict__ outc) {
  __shared__ float4 buf4[512];     // 8 KB cross-wave reduce
  __shared__ float s_lds[8 * HID]; // 8 KB
  __shared__ float red[NW * 8];
  __shared__ float p_lds[HID];
  int c = blockIdx.x;
  int t = threadIdx.x;
  int cnt = cur[c];
  if (cnt == 0) return;  // empty cluster: never referenced by k_expand
  int cntL = (cnt < CAP) ? cnt : CAP;
  int w = t >> 6, l = t & 63;
  const int* lp = list + c * CAP;

  // one pass: acc[h] += e[h]*x ; zacc[h] += e[h]; 8 rows in flight per wave
  float4 acc[8];
#pragma unroll
  for (int h = 0; h < 8; ++h) acc[h] = make_float4(0.f, 0.f, 0.f, 0.f);
  float zacc[8];
#pragma unroll
  for (int h = 0; h < 8; ++h) zacc[h] = 0.f;
  const float* xb = x + 4 * l;

#define ROW(NI)                                                                \
  { int nn = (NI);                                                             \
    float4 ea = *(const float4*)(es + (size_t)nn * 8);                         \
    float4 eb4 = *(const float4*)(es + (size_t)nn * 8 + 4);                    \
    float4 xv = *(const float4*)(xb + (size_t)nn * HID);                       \
    float eh[8] = {ea.x, ea.y, ea.z, ea.w, eb4.x, eb4.y, eb4.z, eb4.w};        \
    _Pragma("unroll")                                                          \
    for (int h = 0; h < 8; ++h) {                                              \
      acc[h].x += eh[h] * xv.x; acc[h].y += eh[h] * xv.y;                      \
      acc[h].z += eh[h] * xv.z; acc[h].w += eh[h] * xv.w;                      \
      zacc[h] += eh[h]; } }
  int i = w;
  for (; i + 7 * NW < cntL; i += 8 * NW) {
    int n0 = lp[i],          n1 = lp[i + NW],     n2 = lp[i + 2 * NW],
        n3 = lp[i + 3 * NW], n4 = lp[i + 4 * NW], n5 = lp[i + 5 * NW],
        n6 = lp[i + 6 * NW], n7 = lp[i + 7 * NW];
    ROW(n0) ROW(n1) ROW(n2) ROW(n3) ROW(n4) ROW(n5) ROW(n6) ROW(n7)
  }
  for (; i < cntL; i += NW) ROW(lp[i])
#undef ROW

  // per-wave z partials (zacc identical across the wave's lanes)
#pragma unroll
  for (int h = 0; h < 8; ++h)
    if (l == h) red[w * 8 + h] = zacc[h];
  __syncthreads();
  float zinv[8];
#pragma unroll
  for (int h = 0; h < 8; ++h) {
    float z = 0.f;
#pragma unroll
    for (int w2 = 0; w2 < NW; ++w2) z += red[w2 * 8 + h];
    zinv[h] = (z > 0.f) ? 1.f / z : 0.f;
  }

  // cross-wave reduce + normalize -> s_lds[h][col]
#pragma unroll
  for (int h = 0; h < 8; ++h) {
    __syncthreads();
    buf4[t] = acc[h];
    __syncthreads();
    if (t < 64) {
      float4 s = buf4[t];
#pragma unroll
      for (int w2 = 1; w2 < NW; ++w2) {
        float4 b = buf4[w2 * 64 + t];
        s.x += b.x; s.y += b.y; s.z += b.z; s.w += b.w;
      }
      float sc = zinv[h];
      s.x *= sc; s.y *= sc; s.z *= sc; s.w *= sc;
      *(float4*)&s_lds[h * HID + 4 * t] = s;
    }
  }
  __syncthreads();

  // GEMV1: pooled[o] = (Wv[o,:]·S[head(o),:] + bv[o]) / cnt -- 4 lanes/row, 2 rows/thread
  int grp = t >> 2, q = t & 3;
  float rc = 1.f / (float)cnt;
#pragma unroll
  for (int r = 0; r < 2; ++r) {
    int o = grp + 128 * r;
    const float4* wr = (const float4*)(Wv + (size_t)o * HID);
    const float4* sr = (const float4*)(s_lds + (o >> 5) * HID);
    float a = 0.f;
#pragma unroll
    for (int k = 0; k < 16; ++k) {
      float4 w4 = wr[q + 4 * k];
      float4 s4 = sr[q + 4 * k];
      a += w4.x * s4.x + w4.y * s4.y + w4.z * s4.z + w4.w * s4.w;
    }
    a += __shfl_xor(a, 1);
    a += __shfl_xor(a, 2);
    if (q == 0) p_lds[o] = (a + bv[o]) * rc;
  }
  __syncthreads();
  // GEMV2: outc[c][o] = Wo[o,:]·pooled + bo[o]  (1 KB sequential store)
#pragma unroll
  for (int r = 0; r < 2; ++r) {
    int o = grp + 128 * r;
    const float4* wr = (const float4*)(Wo + (size_t)o * HID);
    const float4* pr = (const float4*)p_lds;
    float a = 0.f;
#pragma unroll
    for (int k = 0; k < 16; ++k) {
      float4 w4 = wr[q + 4 * k];
      float4 p4 = pr[q + 4 * k];
      a += w4.x * p4.x + w4.y * p4.y + w4.z * p4.z + w4.w * p4.w;
    }
    a += __shfl_xor(a, 1);
    a += __shfl_xor(a, 2);
    if (q == 0) outc[(size_t)c * HID + o] = a + bo[o];
  }
}

// ---- expand: out[n] = outc[seg[n]] — sequential writes, outc L2-hot ----
__global__ __launch_bounds__(256) void k_expand(const int* __restrict__ seg,
                                                const float* __restrict__ outc,
                                                float* __restrict__ out, int N) {
  size_t g = (size_t)blockIdx.x * blockDim.x + threadIdx.x;
  size_t total = (size_t)N * (HID / 4);
  size_t stride = (size_t)gridDim.x * blockDim.x;
  const float4* oc = (const float4*)outc;
  float4* o4 = (float4*)out;
  for (; g < total; g += stride) {
    int n = (int)(g >> 6);
    int q = (int)(g & 63);
    int c = seg[n];
    o4[g] = oc[(size_t)c * 64 + q];
  }
}

extern "C" void kernel_launch(void* const* d_in, const int* in_sizes, int n_in,
                              void* d_out, int out_size, void* d_ws, size_t ws_size,
                              hipStream_t stream) {
  const float* x = (const float*)d_in[0];
  const int* seg = (const int*)d_in[1];
  // d_in[2] = batch (unused by reference)
  const float* Wk = (const float*)d_in[3];
  const float* bk = (const float*)d_in[4];
  const float* Wv = (const float*)d_in[5];
  const float* bv = (const float*)d_in[6];
  const float* Wo = (const float*)d_in[7];
  const float* bo = (const float*)d_in[8];
  const float* pq = (const float*)d_in[9];
  int N = in_sizes[0] / HID;

  char* ws = (char*)d_ws;
  size_t cur_off = 0;
  auto take = [&](size_t bytes) -> void* {
    void* p = ws + cur_off;
    cur_off += (bytes + 255) & ~(size_t)255;
    return p;
  };
  float* qk = (float*)take((size_t)HEADS * HID * 4);
  float* cb = (float*)take((size_t)HEADS * 4);
  int* cur = (int*)take((size_t)C_CLUST * 4);
  int* list = (int*)take((size_t)C_CLUST * CAP * 4);
  float* es = (float*)take((size_t)N * 8 * 4);
  float* outc = (float*)take((size_t)C_CLUST * HID * 4);

  k_prep<<<HEADS, 256, 0, stream>>>(Wk, bk, pq, qk, cb, cur);
  int ntile = (N + 7) / 8;
  int sb = (ntile + 3) / 4;  // one 8-row tile per wave, 4 waves/block
  k_scores<<<sb, 256, 0, stream>>>(x, seg, qk, cb, es, cur, list, N);
  k_pool<<<C_CLUST, 512, 0, stream>>>(x, es, cur, list, Wv, bv, Wo, bo, outc);
  k_expand<<<2048, 256, 0, stream>>>(seg, outc, (float*)d_out, N);
}